// Round 1
// baseline (8445.426 us; speedup 1.0000x reference)
//
#include <hip/hip_runtime.h>
#include <stdint.h>

static constexpr int S_LEN = 4096;
static constexpr int D_DIM = 1024;
static constexpr int M_ST  = 64;
static constexpr float C_THRESH = 0.9f;
static constexpr float C_EPS    = 1e-12f;

typedef float f4 __attribute__((ext_vector_type(4)));

// merge two per-lane accumulators across lane pairs (xor mask); result:
// lanes with (lane&mask)==0 hold x's pair-sum, others hold y's pair-sum.
__device__ __forceinline__ float mergepair(float x, float y, int mask, int lane) {
  float send = (lane & mask) ? x : y;
  float recv = __shfl_xor(send, mask);
  float keep = (lane & mask) ? y : x;
  return keep + recv;
}

__device__ __forceinline__ float wavesum6(float x) {
  #pragma unroll
  for (int m = 1; m < 64; m <<= 1) x += __shfl_xor(x, m);
  return x;
}

// barrier draining LDS only (keeps global prefetch loads in flight; all VMEM
// ordering in this kernel is same-thread register-dependency based).
__device__ __forceinline__ void wg_barrier() {
  asm volatile("s_waitcnt lgkmcnt(0)" ::: "memory");
  __builtin_amdgcn_s_barrier();
  asm volatile("" ::: "memory");
}

__global__ __launch_bounds__(512, 2)
void sparse_agg_kernel(const float* __restrict__ keys,
                       const float* __restrict__ values,
                       float* __restrict__ out) {
  const int b    = blockIdx.x;
  const int tid  = threadIdx.x;
  const int w    = tid >> 6;    // wave 0..7; wave w owns states 8w..8w+7
  const int lane = tid & 63;    // lane l owns dims {256g + 4l + e}

  const float* __restrict__ kB = keys   + (size_t)b * S_LEN * D_DIM;
  const float* __restrict__ vB = values + (size_t)b * S_LEN * D_DIM;
  float* __restrict__ oB = out + (size_t)b * (M_ST * D_DIM);

  __shared__ __align__(16) float kvbuf[2][2 * D_DIM];  // [k(1024) | v(1024)] x2
  __shared__ float sims_lds[M_ST];
  __shared__ float k2_lds;

  // zero-init this batch's output rows (harness poisons d_out each launch;
  // never-created slots must read 0, and RMW rows start defined).
  {
    f4 z = {0.f, 0.f, 0.f, 0.f};
    #pragma unroll
    for (int i = 0; i < (M_ST * D_DIM) / (512 * 4); ++i)
      *(f4*)(oB + (i * 512 + tid) * 4) = z;
  }

  // centroids in registers: c[j][i] = centroid (8w+j), dim (i>>2)*256 + 4*lane + (i&3)
  float c[8][16];
  #pragma unroll
  for (int j = 0; j < 8; ++j)
    #pragma unroll
    for (int i = 0; i < 16; ++i) c[j][i] = 0.f;

  float norm2_reg = 0.f;  // lane l<8: ||centroid(8w+l)||^2
  float cnt_reg   = 0.f;  // lane l: counts[l] (replicated per wave)
  int   K         = 0;    // replicated per wave (identical by construction)

  // deferred states-row RMW (flushed at the NEXT step, hidden under dots)
  int   pend = 0, pslot = 0, pcreate = 0;
  float pinv = 1.0f;
  f4 pv0 = {0,0,0,0}, pv1 = {0,0,0,0}, pv2 = {0,0,0,0}, pv3 = {0,0,0,0};

  // prologue: stage t=0 into buf0, issue t=1 load
  {
    const float* gp = (tid < 256) ? (kB + tid * 4) : (vB + (tid - 256) * 4);
    f4 val = *(const f4*)gp;
    *(f4*)&kvbuf[0][tid * 4] = val;
  }
  f4 sv_ready;  // data for t+1, written to LDS this step
  {
    const float* gp = (tid < 256) ? (kB + D_DIM + tid * 4)
                                  : (vB + D_DIM + (tid - 256) * 4);
    sv_ready = *(const f4*)gp;
  }
  __syncthreads();  // full barrier once: covers zero-init global stores too

  for (int t = 0; t < S_LEN; ++t) {
    const int cur = t & 1;
    const float* kv = kvbuf[cur];

    // issue prefetch for t+2 (2-deep; consumed as sv_ready next step)
    f4 sv_fly = {0,0,0,0};
    if (t + 2 < S_LEN) {
      const float* gp = (tid < 256) ? (kB + (size_t)(t + 2) * D_DIM + tid * 4)
                                    : (vB + (size_t)(t + 2) * D_DIM + (tid - 256) * 4);
      sv_fly = *(const f4*)gp;
    }

    // deferred RMW part 1: issue old-row loads (latency hides under dots)
    f4 o0 = {0,0,0,0}, o1 = {0,0,0,0}, o2 = {0,0,0,0}, o3 = {0,0,0,0};
    if (pend) {
      const float* rp = oB + pslot * D_DIM + lane * 4;
      o0 = *(const f4*)(rp + 0);
      o1 = *(const f4*)(rp + 256);
      o2 = *(const f4*)(rp + 512);
      o3 = *(const f4*)(rp + 768);
    }

    // ---- phase A: dots of 8 owned centroids with raw k ----
    f4 kg0 = *(const f4*)&kv[  0 + lane * 4];
    f4 kg1 = *(const f4*)&kv[256 + lane * 4];
    f4 kg2 = *(const f4*)&kv[512 + lane * 4];
    f4 kg3 = *(const f4*)&kv[768 + lane * 4];

    float acc[8];
    #pragma unroll
    for (int j = 0; j < 8; ++j) {
      float a = 0.f;
      #pragma unroll
      for (int e = 0; e < 4; ++e) {
        a = fmaf(c[j][0  + e], kg0[e], a);
        a = fmaf(c[j][4  + e], kg1[e], a);
        a = fmaf(c[j][8  + e], kg2[e], a);
        a = fmaf(c[j][12 + e], kg3[e], a);
      }
      acc[j] = a;
    }

    // wave 7 additionally computes ||k||^2 for all
    if (w == 7) {
      float s2 = 0.f;
      #pragma unroll
      for (int e = 0; e < 4; ++e) {
        s2 = fmaf(kg0[e], kg0[e], s2);
        s2 = fmaf(kg1[e], kg1[e], s2);
        s2 = fmaf(kg2[e], kg2[e], s2);
        s2 = fmaf(kg3[e], kg3[e], s2);
      }
      s2 = wavesum6(s2);
      if (lane == 0) k2_lds = s2;
    }

    // merge 8 accumulators: lane l ends holding full dot for state 8w+(l&7)
    float m01 = mergepair(acc[0], acc[1], 1, lane);
    float m23 = mergepair(acc[2], acc[3], 1, lane);
    float m45 = mergepair(acc[4], acc[5], 1, lane);
    float m67 = mergepair(acc[6], acc[7], 1, lane);
    float ma  = mergepair(m01, m23, 2, lane);
    float mb  = mergepair(m45, m67, 2, lane);
    float mm  = mergepair(ma,  mb,  4, lane);
    mm += __shfl_xor(mm, 8);
    mm += __shfl_xor(mm, 16);
    mm += __shfl_xor(mm, 32);

    if (lane < 8)
      sims_lds[w * 8 + lane] = mm * rsqrtf(norm2_reg + C_EPS);

    wg_barrier();  // B: sims + k2 visible

    // deferred RMW part 2: combine + store (loads arrived during phase A)
    if (pend) {
      float* rp = oB + pslot * D_DIM + lane * 4;
      f4 n0, n1, n2, n3;
      #pragma unroll
      for (int e = 0; e < 4; ++e) {
        n0[e] = pcreate ? pv0[e] : fmaf(pv0[e] - o0[e], pinv, o0[e]);
        n1[e] = pcreate ? pv1[e] : fmaf(pv1[e] - o1[e], pinv, o1[e]);
        n2[e] = pcreate ? pv2[e] : fmaf(pv2[e] - o2[e], pinv, o2[e]);
        n3[e] = pcreate ? pv3[e] : fmaf(pv3[e] - o3[e], pinv, o3[e]);
      }
      *(f4*)(rp + 0)   = n0;
      *(f4*)(rp + 256) = n1;
      *(f4*)(rp + 512) = n2;
      *(f4*)(rp + 768) = n3;
      pend = 0;
    }

    // ---- phase C (every wave, redundant & identical): argmax + decision ----
    float sv = (lane < K) ? sims_lds[lane] : -__builtin_inff();
    int   si = lane;
    #pragma unroll
    for (int m = 1; m < 64; m <<= 1) {
      float v2 = __shfl_xor(sv, m);
      int   i2 = __shfl_xor(si, m);
      bool take = (v2 > sv) || ((v2 == sv) && (i2 < si));  // jnp.argmax: first max
      sv = take ? v2 : sv;
      si = take ? i2 : si;
    }
    float krs      = rsqrtf(k2_lds + C_EPS);
    float best_sim = sv * krs;  // krs>0: post-argmax scale is exact for compare
    const bool create = (K == 0) || ((best_sim < C_THRESH) && (K < M_ST));
    const int  slot   = create ? K : si;
    float cnt_old = __shfl(cnt_reg, slot);
    float cnt_new = create ? 1.0f : (cnt_old + 1.0f);
    float inv     = 1.0f / cnt_new;  // denom = old n + 1 = cnt_new
    if (lane == slot) cnt_reg = cnt_new;
    K += create ? 1 : 0;

    // ---- phase E: owner wave updates its centroid + stashes state RMW ----
    if (w == (slot >> 3)) {
      const int j = slot & 7;
      float kk[16];
      #pragma unroll
      for (int e = 0; e < 4; ++e) {
        kk[e] = kg0[e]; kk[4 + e] = kg1[e]; kk[8 + e] = kg2[e]; kk[12 + e] = kg3[e];
      }
      float nsum = 0.f;
      switch (j) {
        #define CASEJ(J) case J: { _Pragma("unroll") \
          for (int i = 0; i < 16; ++i) { \
            float cn = create ? kk[i] : fmaf(kk[i] - c[J][i], inv, c[J][i]); \
            c[J][i] = cn; nsum = fmaf(cn, cn, nsum); } } break;
        CASEJ(0) CASEJ(1) CASEJ(2) CASEJ(3)
        CASEJ(4) CASEJ(5) CASEJ(6) CASEJ(7)
        #undef CASEJ
      }
      float nrm = create ? k2_lds : wavesum6(nsum);
      if (lane == j) norm2_reg = nrm;
      // stash v slices for deferred states-row RMW
      pv0 = *(const f4*)&kv[D_DIM +   0 + lane * 4];
      pv1 = *(const f4*)&kv[D_DIM + 256 + lane * 4];
      pv2 = *(const f4*)&kv[D_DIM + 512 + lane * 4];
      pv3 = *(const f4*)&kv[D_DIM + 768 + lane * 4];
      pend = 1; pslot = slot; pcreate = create ? 1 : 0; pinv = inv;
    }

    // stage write for t+1 (sv_ready loaded a full step ago -> latency covered)
    if (t + 1 < S_LEN)
      *(f4*)&kvbuf[cur ^ 1][tid * 4] = sv_ready;
    sv_ready = sv_fly;

    wg_barrier();  // F: staged k/v visible for next step
  }

  // drain the last pending states-row update
  if (pend) {
    float* rp = oB + pslot * D_DIM + lane * 4;
    f4 o0 = *(const f4*)(rp + 0);
    f4 o1 = *(const f4*)(rp + 256);
    f4 o2 = *(const f4*)(rp + 512);
    f4 o3 = *(const f4*)(rp + 768);
    f4 n0, n1, n2, n3;
    #pragma unroll
    for (int e = 0; e < 4; ++e) {
      n0[e] = pcreate ? pv0[e] : fmaf(pv0[e] - o0[e], pinv, o0[e]);
      n1[e] = pcreate ? pv1[e] : fmaf(pv1[e] - o1[e], pinv, o1[e]);
      n2[e] = pcreate ? pv2[e] : fmaf(pv2[e] - o2[e], pinv, o2[e]);
      n3[e] = pcreate ? pv3[e] : fmaf(pv3[e] - o3[e], pinv, o3[e]);
    }
    *(f4*)(rp + 0)   = n0;
    *(f4*)(rp + 256) = n1;
    *(f4*)(rp + 512) = n2;
    *(f4*)(rp + 768) = n3;
  }
}

extern "C" void kernel_launch(void* const* d_in, const int* in_sizes, int n_in,
                              void* d_out, int out_size, void* d_ws, size_t ws_size,
                              hipStream_t stream) {
  const float* keys   = (const float*)d_in[0];
  const float* values = (const float*)d_in[1];
  float* out = (float*)d_out;
  const int B = in_sizes[0] / (S_LEN * D_DIM);
  sparse_agg_kernel<<<dim3(B), dim3(512), 0, stream>>>(keys, values, out);
}